// Round 6
// baseline (430.407 us; speedup 1.0000x reference)
//
#include <hip/hip_runtime.h>

#define N_NODES 50000
#define N_EDGES 1600000
#define FEAT 128
#define NBLK_SCAN 196   // ceil(50000/256)

// ---------------- CSR build ----------------

__global__ __launch_bounds__(256) void count_kernel(const int* __restrict__ dst,
                                                    int* __restrict__ counts, int n) {
    int i = blockIdx.x * blockDim.x + threadIdx.x;
    int stride = gridDim.x * blockDim.x;
    for (; i < n; i += stride) atomicAdd(&counts[dst[i]], 1);
}

__global__ __launch_bounds__(256) void scanA_kernel(const int* __restrict__ counts,
                                                    int* __restrict__ offsets,
                                                    int* __restrict__ bsum) {
    __shared__ int tmp[256];
    int i = blockIdx.x * 256 + threadIdx.x;
    int v = (i < N_NODES) ? counts[i] : 0;
    tmp[threadIdx.x] = v;
    __syncthreads();
    for (int off = 1; off < 256; off <<= 1) {
        int t = (threadIdx.x >= (unsigned)off) ? tmp[threadIdx.x - off] : 0;
        __syncthreads();
        tmp[threadIdx.x] += t;
        __syncthreads();
    }
    if (i < N_NODES) offsets[i] = tmp[threadIdx.x] - v;   // local exclusive
    if (threadIdx.x == 255) bsum[blockIdx.x] = tmp[255];  // block total
}

__global__ __launch_bounds__(256) void scanB_kernel(const int* __restrict__ bsum,
                                                    int* __restrict__ bbase,
                                                    int* __restrict__ offsets, int nb) {
    __shared__ int tmp[256];
    int v = (threadIdx.x < (unsigned)nb) ? bsum[threadIdx.x] : 0;
    tmp[threadIdx.x] = v;
    __syncthreads();
    for (int off = 1; off < 256; off <<= 1) {
        int t = (threadIdx.x >= (unsigned)off) ? tmp[threadIdx.x - off] : 0;
        __syncthreads();
        tmp[threadIdx.x] += t;
        __syncthreads();
    }
    if (threadIdx.x < (unsigned)nb) bbase[threadIdx.x] = tmp[threadIdx.x] - v;
    if (threadIdx.x == 255) offsets[N_NODES] = tmp[255];  // total edge count
}

__global__ __launch_bounds__(256) void scanC_kernel(int* __restrict__ offsets,
                                                    const int* __restrict__ bbase) {
    int i = blockIdx.x * 256 + threadIdx.x;
    if (i < N_NODES) offsets[i] += bbase[blockIdx.x];
}

__global__ __launch_bounds__(256) void fill_kernel(const int* __restrict__ src,
                                                   const int* __restrict__ dst,
                                                   const int* __restrict__ offsets,
                                                   int* __restrict__ cursor,
                                                   int* __restrict__ csr, int n) {
    int i = blockIdx.x * blockDim.x + threadIdx.x;
    int stride = gridDim.x * blockDim.x;
    for (; i < n; i += stride) {
        int d = dst[i];
        int p = offsets[d] + atomicAdd(&cursor[d], 1);
        csr[p] = src[i];
    }
}

// ---------------- gather-side segment mean ----------------
// one wave per node; lane owns channels {2*lane, 2*lane+1}

__global__ __launch_bounds__(256) void gather_kernel(const float* __restrict__ feat,
                                                     const int* __restrict__ offsets,
                                                     const int* __restrict__ csr,
                                                     float* __restrict__ agg) {
    const int lane = threadIdx.x & 63;
    const int wid = (blockIdx.x * blockDim.x + threadIdx.x) >> 6;
    const int nw = (gridDim.x * blockDim.x) >> 6;
    for (int node = wid; node < N_NODES; node += nw) {
        const int beg = offsets[node];
        const int end = offsets[node + 1];
        float x = 0.f, y = 0.f;
        int j = beg;
        for (; j + 4 <= end; j += 4) {
            int s0 = csr[j], s1 = csr[j + 1], s2 = csr[j + 2], s3 = csr[j + 3];
            float2 v0 = *(const float2*)&feat[s0 * FEAT + 2 * lane];
            float2 v1 = *(const float2*)&feat[s1 * FEAT + 2 * lane];
            float2 v2 = *(const float2*)&feat[s2 * FEAT + 2 * lane];
            float2 v3 = *(const float2*)&feat[s3 * FEAT + 2 * lane];
            x += v0.x + v1.x + v2.x + v3.x;
            y += v0.y + v1.y + v2.y + v3.y;
        }
        for (; j < end; ++j) {
            int s = csr[j];
            float2 v = *(const float2*)&feat[s * FEAT + 2 * lane];
            x += v.x;
            y += v.y;
        }
        int deg = end - beg;
        float scale = 1.0f / (float)(deg > 1 ? deg : 1);
        *(float2*)&agg[node * FEAT + 2 * lane] = make_float2(x * scale, y * scale);
    }
}

// ---------------- dual GEMM + concat + relu ----------------
// block: 256 thr, tile 16 rows x 256 out-cols (128 feat-cols + 128 agg-cols)
// LDS: W 64KB + transposed A tiles 16KB = 80KB -> 2 blocks/CU

__global__ __launch_bounds__(256, 2) void gemm_kernel(const float* __restrict__ feat,
                                                      const float* __restrict__ agg,
                                                      const float* __restrict__ W,
                                                      float* __restrict__ out) {
    __shared__ float Wl[FEAT * FEAT];     // [k][c]
    __shared__ float At[2 * FEAT * 16];   // [mat][k][row]
    const int tid = threadIdx.x;

    for (int idx = tid; idx < FEAT * FEAT / 4; idx += 256)
        ((float4*)Wl)[idx] = ((const float4*)W)[idx];

    const int row0 = blockIdx.x * 16;
    {
        const int pair = tid >> 3;        // 0..31 -> (mat,row)
        const int mat = pair >> 4;
        const int row = pair & 15;
        const int kb = (tid & 7) * 16;    // 16 consecutive k per thread
        const float* src = (mat ? agg : feat) + (size_t)(row0 + row) * FEAT + kb;
        float4 a0 = ((const float4*)src)[0];
        float4 a1 = ((const float4*)src)[1];
        float4 a2 = ((const float4*)src)[2];
        float4 a3 = ((const float4*)src)[3];
        float* dst = &At[mat * FEAT * 16 + row];  // + k*16
        dst[(kb + 0) * 16] = a0.x;  dst[(kb + 1) * 16] = a0.y;
        dst[(kb + 2) * 16] = a0.z;  dst[(kb + 3) * 16] = a0.w;
        dst[(kb + 4) * 16] = a1.x;  dst[(kb + 5) * 16] = a1.y;
        dst[(kb + 6) * 16] = a1.z;  dst[(kb + 7) * 16] = a1.w;
        dst[(kb + 8) * 16] = a2.x;  dst[(kb + 9) * 16] = a2.y;
        dst[(kb + 10) * 16] = a2.z; dst[(kb + 11) * 16] = a2.w;
        dst[(kb + 12) * 16] = a3.x; dst[(kb + 13) * 16] = a3.y;
        dst[(kb + 14) * 16] = a3.z; dst[(kb + 15) * 16] = a3.w;
    }
    __syncthreads();

    const int lane = tid & 63;
    const int wv = tid >> 6;              // 0..3
    const int colg = lane & 15;           // 16 col groups of 4
    const int rowg = lane >> 4;           // 4 row groups of 4
    const int mat = wv >> 1;              // waves 0,1: feat; 2,3: agg
    const int col = (wv & 1) * 64 + colg * 4;

    float4 acc0 = {0, 0, 0, 0}, acc1 = {0, 0, 0, 0}, acc2 = {0, 0, 0, 0}, acc3 = {0, 0, 0, 0};
    const float* at = &At[mat * FEAT * 16 + rowg * 4];  // + k*16
    const float* wp = &Wl[col];                         // + k*128

#pragma unroll 4
    for (int k = 0; k < FEAT; ++k) {
        float4 a = *(const float4*)(at + k * 16);
        float4 w = *(const float4*)(wp + k * 128);
        acc0.x += a.x * w.x; acc0.y += a.x * w.y; acc0.z += a.x * w.z; acc0.w += a.x * w.w;
        acc1.x += a.y * w.x; acc1.y += a.y * w.y; acc1.z += a.y * w.z; acc1.w += a.y * w.w;
        acc2.x += a.z * w.x; acc2.y += a.z * w.y; acc2.z += a.z * w.z; acc2.w += a.z * w.w;
        acc3.x += a.w * w.x; acc3.y += a.w * w.y; acc3.z += a.w * w.z; acc3.w += a.w * w.w;
    }

    const int obase = mat * 128 + col;
    float4 r[4] = {acc0, acc1, acc2, acc3};
#pragma unroll
    for (int i = 0; i < 4; ++i) {
        int row = row0 + rowg * 4 + i;
        float4 v = r[i];
        v.x = fmaxf(v.x, 0.f); v.y = fmaxf(v.y, 0.f);
        v.z = fmaxf(v.z, 0.f); v.w = fmaxf(v.w, 0.f);
        *(float4*)&out[(size_t)row * 256 + obase] = v;
    }
}

// ---------------- launch ----------------

extern "C" void kernel_launch(void* const* d_in, const int* in_sizes, int n_in,
                              void* d_out, int out_size, void* d_ws, size_t ws_size,
                              hipStream_t stream) {
    const float* feat = (const float*)d_in[0];
    const float* W = (const float*)d_in[1];
    const int* esrc = (const int*)d_in[2];
    const int* edst = (const int*)d_in[3];
    float* out = (float*)d_out;

    char* ws = (char*)d_ws;
    int* counts  = (int*)(ws + 0);         // 200000 B
    int* cursor  = (int*)(ws + 200000);    // 200000 B
    int* offsets = (int*)(ws + 400000);    // 200004 B (50001 ints)
    int* bsum    = (int*)(ws + 600064);    // 784 B (pad to 1024)
    int* bbase   = (int*)(ws + 601088);    // 784 B (pad to 1024)
    int* csr     = (int*)(ws + 602112);    // 6.4 MB
    float* agg   = (float*)(ws + 7002112); // 25.6 MB -> total ~32.6 MB

    // zero counts + cursor (ws is re-poisoned to 0xAA before every call)
    hipMemsetAsync(ws, 0, 400000, stream);

    count_kernel<<<2048, 256, 0, stream>>>(edst, counts, N_EDGES);
    scanA_kernel<<<NBLK_SCAN, 256, 0, stream>>>(counts, offsets, bsum);
    scanB_kernel<<<1, 256, 0, stream>>>(bsum, bbase, offsets, NBLK_SCAN);
    scanC_kernel<<<NBLK_SCAN, 256, 0, stream>>>(offsets, bbase);
    fill_kernel<<<2048, 256, 0, stream>>>(esrc, edst, offsets, cursor, csr, N_EDGES);
    gather_kernel<<<12500, 256, 0, stream>>>(feat, offsets, csr, agg);
    gemm_kernel<<<3125, 256, 0, stream>>>(feat, agg, W, out);
}

// Round 7
// 379.131 us; speedup vs baseline: 1.1352x; 1.1352x over previous
//
#include <hip/hip_runtime.h>

#define N_NODES 50000
#define N_EDGES 1600000
#define FEAT 128
#define NBLK_SCAN 196   // ceil(50000/256)

// ---------------- CSR build ----------------

__global__ __launch_bounds__(256) void count_kernel(const int* __restrict__ dst,
                                                    int* __restrict__ counts, int n) {
    int i = blockIdx.x * blockDim.x + threadIdx.x;
    int stride = gridDim.x * blockDim.x;
    for (; i < n; i += stride) {
        int d = __builtin_nontemporal_load(&dst[i]);  // don't pollute L2
        atomicAdd(&counts[d], 1);
    }
}

__global__ __launch_bounds__(256) void scanA_kernel(const int* __restrict__ counts,
                                                    int* __restrict__ offsets,
                                                    int* __restrict__ bsum) {
    __shared__ int tmp[256];
    int i = blockIdx.x * 256 + threadIdx.x;
    int v = (i < N_NODES) ? counts[i] : 0;
    tmp[threadIdx.x] = v;
    __syncthreads();
    for (int off = 1; off < 256; off <<= 1) {
        int t = (threadIdx.x >= (unsigned)off) ? tmp[threadIdx.x - off] : 0;
        __syncthreads();
        tmp[threadIdx.x] += t;
        __syncthreads();
    }
    if (i < N_NODES) offsets[i] = tmp[threadIdx.x] - v;   // local exclusive
    if (threadIdx.x == 255) bsum[blockIdx.x] = tmp[255];  // block total
}

__global__ __launch_bounds__(256) void scanB_kernel(const int* __restrict__ bsum,
                                                    int* __restrict__ bbase,
                                                    int* __restrict__ offsets, int nb) {
    __shared__ int tmp[256];
    int v = (threadIdx.x < (unsigned)nb) ? bsum[threadIdx.x] : 0;
    tmp[threadIdx.x] = v;
    __syncthreads();
    for (int off = 1; off < 256; off <<= 1) {
        int t = (threadIdx.x >= (unsigned)off) ? tmp[threadIdx.x - off] : 0;
        __syncthreads();
        tmp[threadIdx.x] += t;
        __syncthreads();
    }
    if (threadIdx.x < (unsigned)nb) bbase[threadIdx.x] = tmp[threadIdx.x] - v;
    if (threadIdx.x == 255) offsets[N_NODES] = tmp[255];  // total edge count
}

__global__ __launch_bounds__(256) void scanC_kernel(int* __restrict__ offsets,
                                                    const int* __restrict__ bbase) {
    int i = blockIdx.x * 256 + threadIdx.x;
    if (i < N_NODES) offsets[i] += bbase[blockIdx.x];
}

// CSR payload is uint16 (src < 50000 < 65536): 3.2 MB region fits in one XCD L2
// -> scattered stores coalesce in-cache instead of 16x sector write amplification.
__global__ __launch_bounds__(256) void fill_kernel(const int* __restrict__ src,
                                                   const int* __restrict__ dst,
                                                   const int* __restrict__ offsets,
                                                   int* __restrict__ cursor,
                                                   unsigned short* __restrict__ csr, int n) {
    int i = blockIdx.x * blockDim.x + threadIdx.x;
    int stride = gridDim.x * blockDim.x;
    for (; i < n; i += stride) {
        int d = __builtin_nontemporal_load(&dst[i]);
        int s = __builtin_nontemporal_load(&src[i]);
        int p = offsets[d] + atomicAdd(&cursor[d], 1);
        csr[p] = (unsigned short)s;
    }
}

// ---------------- P = feat @ W, relu(P) -> out[:, :128], P -> ws ----------------
// block: 256 thr = 4 waves, tile 32 rows x 128 cols; each wave 16 rows x 64 cols,
// 4x4 per lane. LDS: W 64KB + transposed A tile 16KB = 80KB -> 2 blocks/CU.

__global__ __launch_bounds__(256, 2) void gemmP_kernel(const float* __restrict__ feat,
                                                       const float* __restrict__ W,
                                                       float* __restrict__ P,
                                                       float* __restrict__ out) {
    __shared__ float Wl[FEAT * FEAT];   // [k][c]
    __shared__ float At[FEAT * 32];     // [k][row]
    const int tid = threadIdx.x;

    for (int idx = tid; idx < FEAT * FEAT / 4; idx += 256)
        ((float4*)Wl)[idx] = ((const float4*)W)[idx];

    const int row0 = blockIdx.x * 32;
    {
        const int row = tid >> 3;         // 0..31
        const int kb = (tid & 7) * 16;    // 16 consecutive k per thread
        const int grow = row0 + row;
        float4 a0 = {0,0,0,0}, a1 = {0,0,0,0}, a2 = {0,0,0,0}, a3 = {0,0,0,0};
        if (grow < N_NODES) {
            const float* src = feat + (size_t)grow * FEAT + kb;
            a0 = ((const float4*)src)[0];
            a1 = ((const float4*)src)[1];
            a2 = ((const float4*)src)[2];
            a3 = ((const float4*)src)[3];
        }
        float* dst = &At[row];            // + k*32
        dst[(kb + 0) * 32] = a0.x;  dst[(kb + 1) * 32] = a0.y;
        dst[(kb + 2) * 32] = a0.z;  dst[(kb + 3) * 32] = a0.w;
        dst[(kb + 4) * 32] = a1.x;  dst[(kb + 5) * 32] = a1.y;
        dst[(kb + 6) * 32] = a1.z;  dst[(kb + 7) * 32] = a1.w;
        dst[(kb + 8) * 32] = a2.x;  dst[(kb + 9) * 32] = a2.y;
        dst[(kb + 10) * 32] = a2.z; dst[(kb + 11) * 32] = a2.w;
        dst[(kb + 12) * 32] = a3.x; dst[(kb + 13) * 32] = a3.y;
        dst[(kb + 14) * 32] = a3.z; dst[(kb + 15) * 32] = a3.w;
    }
    __syncthreads();

    const int lane = tid & 63;
    const int wv = tid >> 6;              // 0..3
    const int colg = lane & 15;
    const int rowg = lane >> 4;
    const int rbase = (wv >> 1) * 16;     // 0 or 16
    const int col = (wv & 1) * 64 + colg * 4;

    float4 acc0 = {0,0,0,0}, acc1 = {0,0,0,0}, acc2 = {0,0,0,0}, acc3 = {0,0,0,0};
    const float* at = &At[rbase + rowg * 4];  // + k*32
    const float* wp = &Wl[col];               // + k*128

#pragma unroll 4
    for (int k = 0; k < FEAT; ++k) {
        float4 a = *(const float4*)(at + k * 32);
        float4 w = *(const float4*)(wp + k * 128);
        acc0.x += a.x * w.x; acc0.y += a.x * w.y; acc0.z += a.x * w.z; acc0.w += a.x * w.w;
        acc1.x += a.y * w.x; acc1.y += a.y * w.y; acc1.z += a.y * w.z; acc1.w += a.y * w.w;
        acc2.x += a.z * w.x; acc2.y += a.z * w.y; acc2.z += a.z * w.z; acc2.w += a.z * w.w;
        acc3.x += a.w * w.x; acc3.y += a.w * w.y; acc3.z += a.w * w.z; acc3.w += a.w * w.w;
    }

    float4 r[4] = {acc0, acc1, acc2, acc3};
#pragma unroll
    for (int i = 0; i < 4; ++i) {
        int row = row0 + rbase + rowg * 4 + i;
        if (row < N_NODES) {
            float4 v = r[i];
            *(float4*)&P[(size_t)row * FEAT + col] = v;          // pre-relu, for gather
            v.x = fmaxf(v.x, 0.f); v.y = fmaxf(v.y, 0.f);
            v.z = fmaxf(v.z, 0.f); v.w = fmaxf(v.w, 0.f);
            *(float4*)&out[(size_t)row * 256 + col] = v;         // nodes_rep half
        }
    }
}

// ---------------- gather-side segment mean over P -> relu -> out[:, 128:] ----------
// one wave per node; lane owns channels {2*lane, 2*lane+1}
// agg @ W == segment_mean(feat @ W) by linearity, so gather P (not feat).

__global__ __launch_bounds__(256) void gather_kernel(const float* __restrict__ P,
                                                     const int* __restrict__ offsets,
                                                     const unsigned short* __restrict__ csr,
                                                     float* __restrict__ out) {
    const int lane = threadIdx.x & 63;
    const int wid = (blockIdx.x * blockDim.x + threadIdx.x) >> 6;
    const int nw = (gridDim.x * blockDim.x) >> 6;
    for (int node = wid; node < N_NODES; node += nw) {
        const int beg = offsets[node];
        const int end = offsets[node + 1];
        float x = 0.f, y = 0.f;
        int j = beg;
        for (; j + 4 <= end; j += 4) {
            int s0 = csr[j], s1 = csr[j + 1], s2 = csr[j + 2], s3 = csr[j + 3];
            float2 v0 = *(const float2*)&P[(size_t)s0 * FEAT + 2 * lane];
            float2 v1 = *(const float2*)&P[(size_t)s1 * FEAT + 2 * lane];
            float2 v2 = *(const float2*)&P[(size_t)s2 * FEAT + 2 * lane];
            float2 v3 = *(const float2*)&P[(size_t)s3 * FEAT + 2 * lane];
            x += v0.x + v1.x + v2.x + v3.x;
            y += v0.y + v1.y + v2.y + v3.y;
        }
        for (; j < end; ++j) {
            int s = csr[j];
            float2 v = *(const float2*)&P[(size_t)s * FEAT + 2 * lane];
            x += v.x;
            y += v.y;
        }
        int deg = end - beg;
        float scale = 1.0f / (float)(deg > 1 ? deg : 1);
        float2 o = make_float2(fmaxf(x * scale, 0.f), fmaxf(y * scale, 0.f));
        *(float2*)&out[(size_t)node * 256 + FEAT + 2 * lane] = o;
    }
}

// ---------------- launch ----------------

extern "C" void kernel_launch(void* const* d_in, const int* in_sizes, int n_in,
                              void* d_out, int out_size, void* d_ws, size_t ws_size,
                              hipStream_t stream) {
    const float* feat = (const float*)d_in[0];
    const float* W = (const float*)d_in[1];
    const int* esrc = (const int*)d_in[2];
    const int* edst = (const int*)d_in[3];
    float* out = (float*)d_out;

    char* ws = (char*)d_ws;
    int* counts  = (int*)(ws + 0);               // 200000 B
    int* cursor  = (int*)(ws + 200000);          // 200000 B
    int* offsets = (int*)(ws + 400000);          // 200004 B (50001 ints)
    int* bsum    = (int*)(ws + 600064);          // pad to 1024
    int* bbase   = (int*)(ws + 601088);          // pad to 1024
    unsigned short* csr = (unsigned short*)(ws + 602112);  // 3.2 MB
    float* P     = (float*)(ws + 3802112);       // 25.6 MB -> total ~29.4 MB

    // zero counts + cursor (ws is re-poisoned to 0xAA before every call)
    hipMemsetAsync(ws, 0, 400000, stream);

    count_kernel<<<2048, 256, 0, stream>>>(edst, counts, N_EDGES);
    scanA_kernel<<<NBLK_SCAN, 256, 0, stream>>>(counts, offsets, bsum);
    scanB_kernel<<<1, 256, 0, stream>>>(bsum, bbase, offsets, NBLK_SCAN);
    scanC_kernel<<<NBLK_SCAN, 256, 0, stream>>>(offsets, bbase);
    fill_kernel<<<2048, 256, 0, stream>>>(esrc, edst, offsets, cursor, csr, N_EDGES);
    gemmP_kernel<<<(N_NODES + 31) / 32, 256, 0, stream>>>(feat, W, P, out);
    gather_kernel<<<12500, 256, 0, stream>>>(P, offsets, csr, out);
}

// Round 9
// 336.291 us; speedup vs baseline: 1.2799x; 1.1274x over previous
//
#include <hip/hip_runtime.h>
#include <hip/hip_fp16.h>

#define N_NODES 50000
#define N_EDGES 1600000
#define FEAT 128
#define NBLK_SCAN 196   // ceil(50000/256)

// ---------------- CSR build ----------------

__global__ __launch_bounds__(256) void count_kernel(const int* __restrict__ dst,
                                                    int* __restrict__ counts, int n) {
    int i = blockIdx.x * blockDim.x + threadIdx.x;
    int stride = gridDim.x * blockDim.x;
    for (; i < n; i += stride) {
        int d = __builtin_nontemporal_load(&dst[i]);  // don't pollute L2
        atomicAdd(&counts[d], 1);
    }
}

__global__ __launch_bounds__(256) void scanA_kernel(const int* __restrict__ counts,
                                                    int* __restrict__ offsets,
                                                    int* __restrict__ bsum) {
    __shared__ int tmp[256];
    int i = blockIdx.x * 256 + threadIdx.x;
    int v = (i < N_NODES) ? counts[i] : 0;
    tmp[threadIdx.x] = v;
    __syncthreads();
    for (int off = 1; off < 256; off <<= 1) {
        int t = (threadIdx.x >= (unsigned)off) ? tmp[threadIdx.x - off] : 0;
        __syncthreads();
        tmp[threadIdx.x] += t;
        __syncthreads();
    }
    if (i < N_NODES) offsets[i] = tmp[threadIdx.x] - v;   // local exclusive
    if (threadIdx.x == 255) bsum[blockIdx.x] = tmp[255];  // block total
}

__global__ __launch_bounds__(256) void scanB_kernel(const int* __restrict__ bsum,
                                                    int* __restrict__ bbase,
                                                    int* __restrict__ offsets, int nb) {
    __shared__ int tmp[256];
    int v = (threadIdx.x < (unsigned)nb) ? bsum[threadIdx.x] : 0;
    tmp[threadIdx.x] = v;
    __syncthreads();
    for (int off = 1; off < 256; off <<= 1) {
        int t = (threadIdx.x >= (unsigned)off) ? tmp[threadIdx.x - off] : 0;
        __syncthreads();
        tmp[threadIdx.x] += t;
        __syncthreads();
    }
    if (threadIdx.x < (unsigned)nb) bbase[threadIdx.x] = tmp[threadIdx.x] - v;
    if (threadIdx.x == 255) offsets[N_NODES] = tmp[255];  // total edge count
}

__global__ __launch_bounds__(256) void scanC_kernel(int* __restrict__ offsets,
                                                    const int* __restrict__ bbase) {
    int i = blockIdx.x * 256 + threadIdx.x;
    if (i < N_NODES) offsets[i] += bbase[blockIdx.x];
}

// CSR payload is uint16 (src < 50000 < 65536): 3.2 MB region is L2-friendly,
// avoids the 16x sector write amplification seen with int CSR (round 6).
__global__ __launch_bounds__(256) void fill_kernel(const int* __restrict__ src,
                                                   const int* __restrict__ dst,
                                                   const int* __restrict__ offsets,
                                                   int* __restrict__ cursor,
                                                   unsigned short* __restrict__ csr, int n) {
    int i = blockIdx.x * blockDim.x + threadIdx.x;
    int stride = gridDim.x * blockDim.x;
    for (; i < n; i += stride) {
        int d = __builtin_nontemporal_load(&dst[i]);
        int s = __builtin_nontemporal_load(&src[i]);
        int p = offsets[d] + atomicAdd(&cursor[d], 1);
        csr[p] = (unsigned short)s;
    }
}

// ---------------- P = feat @ W: relu(P) -> out[:, :128] (fp32), P -> Ph (fp16) ----
// block: 256 thr = 4 waves, tile 32 rows x 128 cols; each wave 16 rows x 64 cols,
// 4x4 per lane. LDS: W 64KB + transposed A tile 16KB = 80KB -> 2 blocks/CU.

__global__ __launch_bounds__(256, 2) void gemmP_kernel(const float* __restrict__ feat,
                                                       const float* __restrict__ W,
                                                       __half* __restrict__ Ph,
                                                       float* __restrict__ out) {
    __shared__ float Wl[FEAT * FEAT];   // [k][c]
    __shared__ float At[FEAT * 32];     // [k][row]
    const int tid = threadIdx.x;

    for (int idx = tid; idx < FEAT * FEAT / 4; idx += 256)
        ((float4*)Wl)[idx] = ((const float4*)W)[idx];

    const int row0 = blockIdx.x * 32;
    {
        const int row = tid >> 3;         // 0..31
        const int kb = (tid & 7) * 16;    // 16 consecutive k per thread
        const int grow = row0 + row;
        float4 a0 = {0,0,0,0}, a1 = {0,0,0,0}, a2 = {0,0,0,0}, a3 = {0,0,0,0};
        if (grow < N_NODES) {
            const float* src = feat + (size_t)grow * FEAT + kb;
            a0 = ((const float4*)src)[0];
            a1 = ((const float4*)src)[1];
            a2 = ((const float4*)src)[2];
            a3 = ((const float4*)src)[3];
        }
        float* dst = &At[row];            // + k*32
        dst[(kb + 0) * 32] = a0.x;  dst[(kb + 1) * 32] = a0.y;
        dst[(kb + 2) * 32] = a0.z;  dst[(kb + 3) * 32] = a0.w;
        dst[(kb + 4) * 32] = a1.x;  dst[(kb + 5) * 32] = a1.y;
        dst[(kb + 6) * 32] = a1.z;  dst[(kb + 7) * 32] = a1.w;
        dst[(kb + 8) * 32] = a2.x;  dst[(kb + 9) * 32] = a2.y;
        dst[(kb + 10) * 32] = a2.z; dst[(kb + 11) * 32] = a2.w;
        dst[(kb + 12) * 32] = a3.x; dst[(kb + 13) * 32] = a3.y;
        dst[(kb + 14) * 32] = a3.z; dst[(kb + 15) * 32] = a3.w;
    }
    __syncthreads();

    const int lane = tid & 63;
    const int wv = tid >> 6;              // 0..3
    const int colg = lane & 15;
    const int rowg = lane >> 4;
    const int rbase = (wv >> 1) * 16;     // 0 or 16
    const int col = (wv & 1) * 64 + colg * 4;

    float4 acc0 = {0,0,0,0}, acc1 = {0,0,0,0}, acc2 = {0,0,0,0}, acc3 = {0,0,0,0};
    const float* at = &At[rbase + rowg * 4];  // + k*32
    const float* wp = &Wl[col];               // + k*128

#pragma unroll 4
    for (int k = 0; k < FEAT; ++k) {
        float4 a = *(const float4*)(at + k * 32);
        float4 w = *(const float4*)(wp + k * 128);
        acc0.x += a.x * w.x; acc0.y += a.x * w.y; acc0.z += a.x * w.z; acc0.w += a.x * w.w;
        acc1.x += a.y * w.x; acc1.y += a.y * w.y; acc1.z += a.y * w.z; acc1.w += a.y * w.w;
        acc2.x += a.z * w.x; acc2.y += a.z * w.y; acc2.z += a.z * w.z; acc2.w += a.z * w.w;
        acc3.x += a.w * w.x; acc3.y += a.w * w.y; acc3.z += a.w * w.z; acc3.w += a.w * w.w;
    }

    float4 r[4] = {acc0, acc1, acc2, acc3};
#pragma unroll
    for (int i = 0; i < 4; ++i) {
        int row = row0 + rbase + rowg * 4 + i;
        if (row < N_NODES) {
            float4 v = r[i];
            union { __half2 h2[2]; uint2 u; } pk;
            pk.h2[0] = __floats2half2_rn(v.x, v.y);
            pk.h2[1] = __floats2half2_rn(v.z, v.w);
            *(uint2*)&Ph[(size_t)row * FEAT + col] = pk.u;       // fp16 P for gather
            v.x = fmaxf(v.x, 0.f); v.y = fmaxf(v.y, 0.f);
            v.z = fmaxf(v.z, 0.f); v.w = fmaxf(v.w, 0.f);
            *(float4*)&out[(size_t)row * 256 + col] = v;         // nodes_rep half (exact fp32)
        }
    }
}

// ---------------- gather-side segment mean over fp16 P -> relu -> out[:, 128:] ----
// one wave per node; lane owns channels {2*lane, 2*lane+1} (one __half2 = 4B/lane).
// agg @ W == segment_mean(feat @ W) by linearity. fp32 accumulation.

__global__ __launch_bounds__(256) void gather_kernel(const __half* __restrict__ Ph,
                                                     const int* __restrict__ offsets,
                                                     const unsigned short* __restrict__ csr,
                                                     float* __restrict__ out) {
    const int lane = threadIdx.x & 63;
    const int wid = (blockIdx.x * blockDim.x + threadIdx.x) >> 6;
    const int nw = (gridDim.x * blockDim.x) >> 6;
    for (int node = wid; node < N_NODES; node += nw) {
        const int beg = offsets[node];
        const int end = offsets[node + 1];
        float x = 0.f, y = 0.f;
        int j = beg;
        for (; j + 4 <= end; j += 4) {
            int s0 = csr[j], s1 = csr[j + 1], s2 = csr[j + 2], s3 = csr[j + 3];
            float2 v0 = __half22float2(*(const __half2*)&Ph[(size_t)s0 * FEAT + 2 * lane]);
            float2 v1 = __half22float2(*(const __half2*)&Ph[(size_t)s1 * FEAT + 2 * lane]);
            float2 v2 = __half22float2(*(const __half2*)&Ph[(size_t)s2 * FEAT + 2 * lane]);
            float2 v3 = __half22float2(*(const __half2*)&Ph[(size_t)s3 * FEAT + 2 * lane]);
            x += v0.x + v1.x + v2.x + v3.x;
            y += v0.y + v1.y + v2.y + v3.y;
        }
        for (; j < end; ++j) {
            int s = csr[j];
            float2 v = __half22float2(*(const __half2*)&Ph[(size_t)s * FEAT + 2 * lane]);
            x += v.x;
            y += v.y;
        }
        int deg = end - beg;
        float scale = 1.0f / (float)(deg > 1 ? deg : 1);
        float2 o = make_float2(fmaxf(x * scale, 0.f), fmaxf(y * scale, 0.f));
        *(float2*)&out[(size_t)node * 256 + FEAT + 2 * lane] = o;
    }
}

// ---------------- launch ----------------

extern "C" void kernel_launch(void* const* d_in, const int* in_sizes, int n_in,
                              void* d_out, int out_size, void* d_ws, size_t ws_size,
                              hipStream_t stream) {
    const float* feat = (const float*)d_in[0];
    const float* W = (const float*)d_in[1];
    const int* esrc = (const int*)d_in[2];
    const int* edst = (const int*)d_in[3];
    float* out = (float*)d_out;

    char* ws = (char*)d_ws;
    int* counts  = (int*)(ws + 0);               // 200000 B
    int* cursor  = (int*)(ws + 200000);          // 200000 B
    int* offsets = (int*)(ws + 400000);          // 200004 B (50001 ints)
    int* bsum    = (int*)(ws + 600064);          // pad to 1024
    int* bbase   = (int*)(ws + 601088);          // pad to 1024
    unsigned short* csr = (unsigned short*)(ws + 602112);  // 3.2 MB
    __half* Ph   = (__half*)(ws + 3802112);      // 12.8 MB -> total ~16.6 MB

    // zero counts + cursor (ws is re-poisoned to 0xAA before every call)
    hipMemsetAsync(ws, 0, 400000, stream);

    count_kernel<<<2048, 256, 0, stream>>>(edst, counts, N_EDGES);
    scanA_kernel<<<NBLK_SCAN, 256, 0, stream>>>(counts, offsets, bsum);
    scanB_kernel<<<1, 256, 0, stream>>>(bsum, bbase, offsets, NBLK_SCAN);
    scanC_kernel<<<NBLK_SCAN, 256, 0, stream>>>(offsets, bbase);
    fill_kernel<<<2048, 256, 0, stream>>>(esrc, edst, offsets, cursor, csr, N_EDGES);
    gemmP_kernel<<<(N_NODES + 31) / 32, 256, 0, stream>>>(feat, W, Ph, out);
    gather_kernel<<<12500, 256, 0, stream>>>(Ph, offsets, csr, out);
}